// Round 1
// baseline (1898.641 us; speedup 1.0000x reference)
//
#include <hip/hip_runtime.h>
#include <math.h>

#define SEQL 4096
#define DIMM 4096
#define NH 32
#define NKV 8
#define HD 128
#define CH 128
#define NCH 32

typedef unsigned short u16;
typedef unsigned int u32;
typedef __attribute__((ext_vector_type(2))) u16 u16x2;
typedef __attribute__((ext_vector_type(4))) u16 u16x4;
typedef __attribute__((ext_vector_type(8))) u16 u16x8;
typedef __attribute__((ext_vector_type(4))) u32 u32x4;
typedef __attribute__((ext_vector_type(4))) float f32x4;
typedef __attribute__((ext_vector_type(8))) __bf16 bf16x8;

__device__ __forceinline__ u16 f2bf(float f) {
  u32 u = __builtin_bit_cast(u32, f);
  u32 r = u + 0x7fffu + ((u >> 16) & 1u);
  return (u16)(r >> 16);
}

__device__ __forceinline__ f32x4 mfma16(bf16x8 a, bf16x8 b, f32x4 c) {
  return __builtin_amdgcn_mfma_f32_16x16x32_bf16(a, b, c, 0, 0, 0);
}

// XOR swizzle for [rows][128] bf16 LDS tiles: spreads the 256B-row-stride
// column reads across banks; preserves 16B alignment (bits 4..7 only).
__device__ __forceinline__ u16* swz(u16* base, int row, int col) {
  unsigned byte = (unsigned)(row * 256 + col * 2);
  byte ^= (unsigned)((row & 15) << 4);
  return (u16*)((char*)base + byte);
}

// ---------------- f32 -> bf16 convert ----------------
__global__ __launch_bounds__(256) void k_cvt(const float* __restrict__ s,
                                             u16* __restrict__ d, int n4) {
  int i = blockIdx.x * 256 + threadIdx.x;
  if (i >= n4) return;
  float4 v = ((const float4*)s)[i];
  u16x4 o = { f2bf(v.x), f2bf(v.y), f2bf(v.z), f2bf(v.w) };
  ((u16x4*)d)[i] = o;
}

// ---------------- NT GEMM: C[M,N] = A[M,K] * B[N,K]^T (bf16 in, f32 out) ----
#define LDK 72  // BK=64 + 8 pad -> 144B row stride (16B-aligned, 2-way-free reads)
__global__ __launch_bounds__(256, 2) void k_gemm_nt(
    const u16* __restrict__ A, const u16* __restrict__ B, float* __restrict__ C,
    int M, int N, int K) {
  __shared__ __align__(16) u16 Al[128][LDK];
  __shared__ __align__(16) u16 Bl[128][LDK];
  const int t = threadIdx.x, lane = t & 63, w = t >> 6;
  const int wm = w >> 1, wn = w & 1, l15 = lane & 15, l4 = lane >> 4;
  const int bm = blockIdx.y, bn = blockIdx.x;
  const int srow = t >> 3, scol = (t & 7) * 8;
  const u16* ga = A + (size_t)(bm * 128 + srow) * K + scol;
  const u16* gb = B + (size_t)(bn * 128 + srow) * K + scol;
  f32x4 acc[4][4] = {};
  for (int kt = 0; kt < K; kt += 64) {
#pragma unroll
    for (int i = 0; i < 4; ++i) {
      *(u32x4*)&Al[srow + i * 32][scol] = *(const u32x4*)(ga + (size_t)i * 32 * K + kt);
      *(u32x4*)&Bl[srow + i * 32][scol] = *(const u32x4*)(gb + (size_t)i * 32 * K + kt);
    }
    __syncthreads();
#pragma unroll
    for (int kk = 0; kk < 2; ++kk) {
      bf16x8 af[4], bfr[4];
#pragma unroll
      for (int m = 0; m < 4; ++m)
        af[m] = *(const bf16x8*)&Al[wm * 64 + m * 16 + l15][kk * 32 + l4 * 8];
#pragma unroll
      for (int n = 0; n < 4; ++n)
        bfr[n] = *(const bf16x8*)&Bl[wn * 64 + n * 16 + l15][kk * 32 + l4 * 8];
#pragma unroll
      for (int m = 0; m < 4; ++m)
#pragma unroll
        for (int n = 0; n < 4; ++n)
          acc[m][n] = mfma16(af[m], bfr[n], acc[m][n]);
    }
    __syncthreads();
  }
#pragma unroll
  for (int m = 0; m < 4; ++m) {
    const int r0 = bm * 128 + wm * 64 + m * 16 + l4 * 4;
#pragma unroll
    for (int n = 0; n < 4; ++n) {
      const int cc = bn * 128 + wn * 64 + n * 16 + l15;
#pragma unroll
      for (int i = 0; i < 4; ++i)
        C[(size_t)(r0 + i) * N + cc] = acc[m][n][i];
    }
  }
}

// ---------------- RoPE + row-softmax on Q -> bf16 [b][h][s][d] -------------
__global__ __launch_bounds__(256) void k_rope_sm_q(
    const float* __restrict__ xq, const float* __restrict__ fc,
    u16* __restrict__ qsm) {
  const int gw = blockIdx.x * 4 + (threadIdx.x >> 6);
  const int lane = threadIdx.x & 63;
  const int b = gw >> 17, s = (gw >> 5) & 4095, h = gw & 31;
  const float2 v = ((const float2*)(xq + ((size_t)(b * SEQL + s)) * DIMM + h * HD))[lane];
  const float2 cs = ((const float2*)fc)[s * 64 + lane];
  const float r0 = v.x * cs.x - v.y * cs.y;
  const float r1 = v.x * cs.y + v.y * cs.x;
  float mx = fmaxf(r0, r1);
#pragma unroll
  for (int o = 32; o > 0; o >>= 1) mx = fmaxf(mx, __shfl_xor(mx, o));
  const float e0 = __expf(r0 - mx), e1 = __expf(r1 - mx);
  float sm = e0 + e1;
#pragma unroll
  for (int o = 32; o > 0; o >>= 1) sm += __shfl_xor(sm, o);
  const float inv = 1.0f / sm;
  u16x2 o2 = { f2bf(e0 * inv), f2bf(e1 * inv) };
  *(u16x2*)(qsm + (((size_t)(b * NH + h) * SEQL + s) * HD) + lane * 2) = o2;
}

// ------- per-(b,kvh,chunk): RoPE(k), column max/expsum, B = e^T v (MFMA) ----
__global__ __launch_bounds__(256) void k_chunk_stats(
    const float* __restrict__ xk, const float* __restrict__ xv,
    const float* __restrict__ fc, float* __restrict__ mloc,
    float* __restrict__ aloc, float* __restrict__ bloc) {
  const int bid = blockIdx.x;                    // (b*NKV+kvh)*NCH + nc
  const int nc = bid & 31, kvh = (bid >> 5) & 7, b = bid >> 8;
  __shared__ __align__(16) float klds[CH][HD];   // 64KB: rotated k, [c][d]
  __shared__ __align__(16) u16 eT[HD * HD];      // 32KB: e^T [d][c], swizzled
  __shared__ __align__(16) u16 vT[HD * HD];      // 32KB: v^T [e][c], swizzled
  __shared__ float red[2][HD];
  const int t = threadIdx.x;
  const int s0 = nc * CH;
  for (int i = 0; i < 32; ++i) {
    const int idx = i * 256 + t;
    const int c = idx >> 6, p = idx & 63;
    const size_t g = ((size_t)(b * SEQL + s0 + c)) * (NKV * HD) + kvh * HD + p * 2;
    const float2 kk = *(const float2*)(xk + g);
    const float2 cs = ((const float2*)fc)[(s0 + c) * 64 + p];
    klds[c][p * 2]     = kk.x * cs.x - kk.y * cs.y;
    klds[c][p * 2 + 1] = kk.x * cs.y + kk.y * cs.x;
    const float2 vv = *(const float2*)(xv + g);
    *swz(vT, p * 2, c)     = f2bf(vv.x);
    *swz(vT, p * 2 + 1, c) = f2bf(vv.y);
  }
  __syncthreads();
  const int d = t & 127, part = t >> 7;
  const int cbeg = part * 64;
  float mx = -INFINITY;
  for (int c = cbeg; c < cbeg + 64; ++c) mx = fmaxf(mx, klds[c][d]);
  red[part][d] = mx;
  __syncthreads();
  const float m = fmaxf(red[0][d], red[1][d]);
  __syncthreads();
  float sum = 0.f;
  for (int c = cbeg; c < cbeg + 64; ++c) {
    const float e = __expf(klds[c][d] - m);
    sum += e;
    *swz(eT, d, c) = f2bf(e);
  }
  red[part][d] = sum;
  __syncthreads();
  const float Av = red[0][d] + red[1][d];
  if (part == 0) {
    mloc[(size_t)bid * HD + d] = m;
    aloc[(size_t)bid * HD + d] = Av;
  }
  // B[d][e] = sum_c eT[d][c] * vT[e][c]
  const int lane = t & 63, w = t >> 6, wm = w >> 1, wn = w & 1;
  const int l15 = lane & 15, l4 = lane >> 4;
  f32x4 acc[4][4] = {};
#pragma unroll
  for (int kk2 = 0; kk2 < 4; ++kk2) {
    bf16x8 af[4], bfr[4];
#pragma unroll
    for (int mm = 0; mm < 4; ++mm)
      af[mm] = *(const bf16x8*)swz(eT, wm * 64 + mm * 16 + l15, kk2 * 32 + l4 * 8);
#pragma unroll
    for (int nn = 0; nn < 4; ++nn)
      bfr[nn] = *(const bf16x8*)swz(vT, wn * 64 + nn * 16 + l15, kk2 * 32 + l4 * 8);
#pragma unroll
    for (int mm = 0; mm < 4; ++mm)
#pragma unroll
      for (int nn = 0; nn < 4; ++nn)
        acc[mm][nn] = mfma16(af[mm], bfr[nn], acc[mm][nn]);
  }
  float* bout = bloc + (size_t)bid * HD * HD;
#pragma unroll
  for (int mm = 0; mm < 4; ++mm) {
    const int r0 = wm * 64 + mm * 16 + l4 * 4;
#pragma unroll
    for (int nn = 0; nn < 4; ++nn) {
      const int cc = wn * 64 + nn * 16 + l15;
#pragma unroll
      for (int i = 0; i < 4; ++i)
        bout[(size_t)(r0 + i) * HD + cc] = acc[mm][nn][i];
    }
  }
}

// ------- online scan over 32 chunks: kv[nc][bk][d][e] = B_run/A_run --------
__global__ __launch_bounds__(256) void k_scan_kv(
    const float* __restrict__ mloc, const float* __restrict__ aloc,
    const float* __restrict__ bloc, u16* __restrict__ kv) {
  const int gw = blockIdx.x * 4 + (threadIdx.x >> 6);  // (bk)*128 + d
  const int lane = threadIdx.x & 63;
  const int d = gw & 127, bk = gw >> 7;
  float m = -INFINITY, A = 0.f, B0 = 0.f, B1 = 0.f;
  for (int nc = 0; nc < NCH; ++nc) {
    const size_t sb = ((size_t)bk * NCH + nc) * HD + d;
    const float ml = mloc[sb], Alc = aloc[sb];
    const float2 Bl = *(const float2*)(bloc + sb * HD + lane * 2);
    const float mn = fmaxf(m, ml);
    const float so = __expf(m - mn), sn = __expf(ml - mn);
    A = A * so + Alc * sn;
    B0 = B0 * so + Bl.x * sn;
    B1 = B1 * so + Bl.y * sn;
    m = mn;
    const float inv = 1.0f / A;
    u16x2 o = { f2bf(B0 * inv), f2bf(B1 * inv) };
    *(u16x2*)(kv + (((size_t)nc * 16 + bk) * HD + d) * HD + lane * 2) = o;
  }
}

// ------- per-(b,h,chunk): attn[c][e] = q_sm[c][:] @ kv[:][e] (MFMA) --------
__global__ __launch_bounds__(256) void k_attn_out(
    const u16* __restrict__ qsm, const u16* __restrict__ kv,
    u16* __restrict__ attn) {
  const int bid = blockIdx.x;                    // (b*NH+h)*NCH + nc
  const int nc = bid & 31, h = (bid >> 5) & 31, b = bid >> 10;
  const int bk = b * 8 + (h >> 2);
  __shared__ __align__(16) u16 ql[CH * HD];      // [c][d] swizzled
  __shared__ __align__(16) u16 kvT[HD * HD];     // [e][d] swizzled
  const int t = threadIdx.x;
  const u16* qbase = qsm + ((size_t)(b * NH + h) * SEQL + nc * CH) * HD;
#pragma unroll
  for (int i = 0; i < 8; ++i) {
    const int idx = i * 256 + t;
    const int c = idx >> 4, col = (idx & 15) * 8;
    *(u16x8*)swz(ql, c, col) = *(const u16x8*)(qbase + (size_t)c * HD + col);
  }
  const u16* kvbase = kv + ((size_t)nc * 16 + bk) * HD * HD;
  for (int i = 0; i < 32; ++i) {
    const int idx = i * 256 + t;
    const int dd = idx >> 6, e0 = (idx & 63) * 2;
    const u16x2 p = *(const u16x2*)(kvbase + (size_t)dd * HD + e0);
    *swz(kvT, e0, dd) = p[0];
    *swz(kvT, e0 + 1, dd) = p[1];
  }
  __syncthreads();
  const int lane = t & 63, w = t >> 6, wm = w >> 1, wn = w & 1;
  const int l15 = lane & 15, l4 = lane >> 4;
  f32x4 acc[4][4] = {};
#pragma unroll
  for (int kk2 = 0; kk2 < 4; ++kk2) {
    bf16x8 af[4], bfr[4];
#pragma unroll
    for (int mm = 0; mm < 4; ++mm)
      af[mm] = *(const bf16x8*)swz(ql, wm * 64 + mm * 16 + l15, kk2 * 32 + l4 * 8);
#pragma unroll
    for (int nn = 0; nn < 4; ++nn)
      bfr[nn] = *(const bf16x8*)swz(kvT, wn * 64 + nn * 16 + l15, kk2 * 32 + l4 * 8);
#pragma unroll
    for (int mm = 0; mm < 4; ++mm)
#pragma unroll
      for (int nn = 0; nn < 4; ++nn)
        acc[mm][nn] = mfma16(af[mm], bfr[nn], acc[mm][nn]);
  }
  u16* obase = attn + ((size_t)(b * SEQL + nc * CH)) * DIMM + h * HD;
#pragma unroll
  for (int mm = 0; mm < 4; ++mm) {
    const int r0 = wm * 64 + mm * 16 + l4 * 4;
#pragma unroll
    for (int nn = 0; nn < 4; ++nn) {
      const int cc = wn * 64 + nn * 16 + l15;
#pragma unroll
      for (int i = 0; i < 4; ++i)
        obase[(size_t)(r0 + i) * DIMM + cc] = f2bf(acc[mm][nn][i]);
    }
  }
}

extern "C" void kernel_launch(void* const* d_in, const int* in_sizes, int n_in,
                              void* d_out, int out_size, void* d_ws, size_t ws_size,
                              hipStream_t stream) {
  const float* x  = (const float*)d_in[0];
  const float* fc = (const float*)d_in[1];
  const float* wq = (const float*)d_in[2];
  const float* wk = (const float*)d_in[3];
  const float* wv = (const float*)d_in[4];
  const float* wo = (const float*)d_in[5];
  float* out = (float*)d_out;
  char* ws = (char*)d_ws;
  size_t off = 0;
  auto take = [&](size_t bytes) {
    char* p = ws + off;
    off += (bytes + 255) & ~(size_t)255;
    return p;
  };
  u16* xb   = (u16*)take((size_t)8192 * 4096 * 2);   //  64 MiB
  u16* wqb  = (u16*)take((size_t)4096 * 4096 * 2);   //  32 MiB
  u16* wkb  = (u16*)take((size_t)1024 * 4096 * 2);   //   8 MiB
  u16* wvb  = (u16*)take((size_t)1024 * 4096 * 2);   //   8 MiB
  u16* wob  = (u16*)take((size_t)4096 * 4096 * 2);   //  32 MiB
  float* xq = (float*)take((size_t)8192 * 4096 * 4); // 128 MiB
  float* xk = (float*)take((size_t)8192 * 1024 * 4); //  32 MiB
  float* xv = (float*)take((size_t)8192 * 1024 * 4); //  32 MiB
  u16* qsm  = (u16*)take((size_t)8192 * 4096 * 2);   //  64 MiB
  float* mloc = (float*)take((size_t)512 * 128 * 4);
  float* aloc = (float*)take((size_t)512 * 128 * 4);
  u16* kvb  = (u16*)take((size_t)512 * 128 * 128 * 2); // 16 MiB
  // aliases (safe by stream ordering): bloc written after xq is consumed,
  // attn written after xk/xv are consumed.
  float* bloc = xq;
  u16* attn = (u16*)xk;

  k_cvt<<<8388608 / 256, 256, 0, stream>>>(x,  xb,  8388608);
  k_cvt<<<4194304 / 256, 256, 0, stream>>>(wq, wqb, 4194304);
  k_cvt<<<1048576 / 256, 256, 0, stream>>>(wk, wkb, 1048576);
  k_cvt<<<1048576 / 256, 256, 0, stream>>>(wv, wvb, 1048576);
  k_cvt<<<4194304 / 256, 256, 0, stream>>>(wo, wob, 4194304);

  k_gemm_nt<<<dim3(32, 64), 256, 0, stream>>>(xb, wqb, xq, 8192, 4096, 4096);
  k_gemm_nt<<<dim3(8, 64),  256, 0, stream>>>(xb, wkb, xk, 8192, 1024, 4096);
  k_gemm_nt<<<dim3(8, 64),  256, 0, stream>>>(xb, wvb, xv, 8192, 1024, 4096);

  k_rope_sm_q<<<65536, 256, 0, stream>>>(xq, fc, qsm);
  k_chunk_stats<<<512, 256, 0, stream>>>(xk, xv, fc, mloc, aloc, bloc);
  k_scan_kv<<<512, 256, 0, stream>>>(mloc, aloc, bloc, kvb);
  k_attn_out<<<2048, 256, 0, stream>>>(qsm, kvb, attn);

  k_gemm_nt<<<dim3(32, 64), 256, 0, stream>>>(attn, wob, out, 8192, 4096, 4096);
}

// Round 2
// 1471.970 us; speedup vs baseline: 1.2899x; 1.2899x over previous
//
#include <hip/hip_runtime.h>
#include <math.h>

#define SEQL 4096
#define DIMM 4096
#define NH 32
#define NKV 8
#define HD 128
#define CH 128
#define NCH 32

typedef unsigned short u16;
typedef unsigned int u32;
typedef __attribute__((ext_vector_type(2))) u16 u16x2;
typedef __attribute__((ext_vector_type(4))) u16 u16x4;
typedef __attribute__((ext_vector_type(8))) u16 u16x8;
typedef __attribute__((ext_vector_type(4))) u32 u32x4;
typedef __attribute__((ext_vector_type(4))) float f32x4;
typedef __attribute__((ext_vector_type(8))) __bf16 bf16x8;

__device__ __forceinline__ u16 f2bf(float f) {
  u32 u = __builtin_bit_cast(u32, f);
  u32 r = u + 0x7fffu + ((u >> 16) & 1u);
  return (u16)(r >> 16);
}

__device__ __forceinline__ f32x4 mfma16(bf16x8 a, bf16x8 b, f32x4 c) {
  return __builtin_amdgcn_mfma_f32_16x16x32_bf16(a, b, c, 0, 0, 0);
}

// async global->LDS, 16B per lane; LDS dest = wave-uniform base + lane*16
__device__ __forceinline__ void gload16(const void* g, void* l) {
  __builtin_amdgcn_global_load_lds(
      (const __attribute__((address_space(1))) void*)g,
      (__attribute__((address_space(3))) void*)l, 16, 0, 0);
}

// XOR swizzle for [rows][128] bf16 LDS tiles (attention-side kernels).
__device__ __forceinline__ u16* swz(u16* base, int row, int col) {
  unsigned byte = (unsigned)(row * 256 + col * 2);
  byte ^= (unsigned)((row & 15) << 4);
  return (u16*)((char*)base + byte);
}

// ---------------- f32 -> bf16 convert ----------------
__global__ __launch_bounds__(256) void k_cvt(const float* __restrict__ s,
                                             u16* __restrict__ d, int n4) {
  int i = blockIdx.x * 256 + threadIdx.x;
  if (i >= n4) return;
  float4 v = ((const float4*)s)[i];
  u16x4 o = { f2bf(v.x), f2bf(v.y), f2bf(v.z), f2bf(v.w) };
  ((u16x4*)d)[i] = o;
}

// --------- NT GEMM (m97 structure): C[M,N] = A[M,K] * B[N,K]^T -------------
// EPI=0: f32 C write. EPI=1: fused RoPE + row-softmax -> bf16 qsm[b][h][s][d].
template <int EPI>
__global__ __launch_bounds__(256) void k_gemm(
    const u16* __restrict__ A, const u16* __restrict__ B, void* __restrict__ Cout,
    const float* __restrict__ fc, int M, int N, int K) {
  __shared__ __align__(16) u16 Al[128][64];
  __shared__ __align__(16) u16 Bl[128][64];
  const int t = threadIdx.x, lane = t & 63, w = t >> 6;
  const int wm = w >> 1, wn = w & 1, l15 = lane & 15, l4 = lane >> 4;
  const int bm = blockIdx.y, bn = blockIdx.x;
  // staging: wave w owns rows w*32..w*32+31 of each tile; 4 insts of 8 rows
  const int srow = w * 32 + (lane >> 3);
  const int scol = (lane & 7) * 8;
  const u16* ga = A + (size_t)(bm * 128 + srow) * K + scol;
  const u16* gb = B + (size_t)(bn * 128 + srow) * K + scol;
  f32x4 acc[4][4] = {};
  for (int kt = 0; kt < K; kt += 64) {
#pragma unroll
    for (int j = 0; j < 4; ++j) {
      gload16(ga + (size_t)j * 8 * K + kt, &Al[w * 32 + j * 8][0]);
      gload16(gb + (size_t)j * 8 * K + kt, &Bl[w * 32 + j * 8][0]);
    }
    __syncthreads();
#pragma unroll
    for (int kk = 0; kk < 2; ++kk) {
      bf16x8 af[4], bfr[4];
#pragma unroll
      for (int m = 0; m < 4; ++m)
        af[m] = *(const bf16x8*)&Al[wm * 64 + m * 16 + l15][kk * 32 + l4 * 8];
#pragma unroll
      for (int n = 0; n < 4; ++n)
        bfr[n] = *(const bf16x8*)&Bl[wn * 64 + n * 16 + l15][kk * 32 + l4 * 8];
#pragma unroll
      for (int m = 0; m < 4; ++m)
#pragma unroll
        for (int n = 0; n < 4; ++n)
          acc[m][n] = mfma16(af[m], bfr[n], acc[m][n]);
    }
    __syncthreads();
  }

  if constexpr (EPI == 0) {
    float* C = (float*)Cout;
#pragma unroll
    for (int m = 0; m < 4; ++m) {
      const int r0 = bm * 128 + wm * 64 + m * 16 + l4 * 4;
#pragma unroll
      for (int n = 0; n < 4; ++n) {
        const int cc = bn * 128 + wn * 64 + n * 16 + l15;
#pragma unroll
        for (int i = 0; i < 4; ++i)
          C[(size_t)(r0 + i) * N + cc] = acc[m][n][i];
      }
    }
  } else {
    // Fused RoPE + per-row softmax. Block tile = 128 seq rows x one head (bn).
    __shared__ float redmx[2][128];
    __shared__ float redsm[2][128];
    const int b = bm >> 5;
    const int s0 = (bm & 31) * 128;
    const int h = bn;
    // RoPE: pair partner lives in lane^1 (col^1), same row.
#pragma unroll
    for (int m = 0; m < 4; ++m)
#pragma unroll
      for (int n = 0; n < 4; ++n) {
        const int c = wn * 64 + n * 16 + l15;
        const int p = c >> 1;
        const bool odd = c & 1;
#pragma unroll
        for (int i = 0; i < 4; ++i) {
          const int row = wm * 64 + m * 16 + l4 * 4 + i;
          const float2 cs = *(const float2*)(fc + (size_t)(s0 + row) * 128 + p * 2);
          const float self = acc[m][n][i];
          const float other = __shfl_xor(self, 1);
          acc[m][n][i] = odd ? (other * cs.y + self * cs.x)
                             : (self * cs.x - other * cs.y);
        }
      }
    // row max: reduce over n, then 16-lane butterfly, then cross-wave via LDS
    float mx[4][4];
#pragma unroll
    for (int m = 0; m < 4; ++m)
#pragma unroll
      for (int i = 0; i < 4; ++i) {
        float v = fmaxf(fmaxf(acc[m][0][i], acc[m][1][i]),
                        fmaxf(acc[m][2][i], acc[m][3][i]));
#pragma unroll
        for (int o = 8; o > 0; o >>= 1) v = fmaxf(v, __shfl_xor(v, o));
        mx[m][i] = v;
      }
    if (l15 == 0) {
#pragma unroll
      for (int m = 0; m < 4; ++m)
#pragma unroll
        for (int i = 0; i < 4; ++i)
          redmx[wn][wm * 64 + m * 16 + l4 * 4 + i] = mx[m][i];
    }
    __syncthreads();
    float sm[4][4];
#pragma unroll
    for (int m = 0; m < 4; ++m)
#pragma unroll
      for (int i = 0; i < 4; ++i) {
        const int row = wm * 64 + m * 16 + l4 * 4 + i;
        const float mr = fmaxf(redmx[0][row], redmx[1][row]);
        float s = 0.f;
#pragma unroll
        for (int n = 0; n < 4; ++n) {
          acc[m][n][i] = __expf(acc[m][n][i] - mr);
          s += acc[m][n][i];
        }
#pragma unroll
        for (int o = 8; o > 0; o >>= 1) s += __shfl_xor(s, o);
        sm[m][i] = s;
      }
    if (l15 == 0) {
#pragma unroll
      for (int m = 0; m < 4; ++m)
#pragma unroll
        for (int i = 0; i < 4; ++i)
          redsm[wn][wm * 64 + m * 16 + l4 * 4 + i] = sm[m][i];
    }
    __syncthreads();
    u16* qout = (u16*)Cout;
#pragma unroll
    for (int m = 0; m < 4; ++m)
#pragma unroll
      for (int i = 0; i < 4; ++i) {
        const int row = wm * 64 + m * 16 + l4 * 4 + i;
        const float inv = 1.0f / (redsm[0][row] + redsm[1][row]);
        u16* base = qout + ((size_t)(b * NH + h) * SEQL + s0 + row) * HD;
#pragma unroll
        for (int n = 0; n < 4; ++n)
          base[wn * 64 + n * 16 + l15] = f2bf(acc[m][n][i] * inv);
      }
  }
}

// ------- per-(b,kvh,chunk): RoPE(k), column max/expsum, B = e^T v (MFMA) ----
__global__ __launch_bounds__(256) void k_chunk_stats(
    const float* __restrict__ xk, const float* __restrict__ xv,
    const float* __restrict__ fc, float* __restrict__ mloc,
    float* __restrict__ aloc, float* __restrict__ bloc) {
  const int bid = blockIdx.x;                    // (b*NKV+kvh)*NCH + nc
  const int nc = bid & 31, kvh = (bid >> 5) & 7, b = bid >> 8;
  __shared__ __align__(16) float klds[CH][HD];   // rotated k, [c][d]
  __shared__ __align__(16) u16 eT[HD * HD];      // e^T [d][c], swizzled
  __shared__ __align__(16) u16 vT[HD * HD];      // v^T [e][c], swizzled
  __shared__ float red[2][HD];
  const int t = threadIdx.x;
  const int s0 = nc * CH;
  for (int i = 0; i < 32; ++i) {
    const int idx = i * 256 + t;
    const int c = idx >> 6, p = idx & 63;
    const size_t g = ((size_t)(b * SEQL + s0 + c)) * (NKV * HD) + kvh * HD + p * 2;
    const float2 kk = *(const float2*)(xk + g);
    const float2 cs = ((const float2*)fc)[(s0 + c) * 64 + p];
    klds[c][p * 2]     = kk.x * cs.x - kk.y * cs.y;
    klds[c][p * 2 + 1] = kk.x * cs.y + kk.y * cs.x;
    const float2 vv = *(const float2*)(xv + g);
    *swz(vT, p * 2, c)     = f2bf(vv.x);
    *swz(vT, p * 2 + 1, c) = f2bf(vv.y);
  }
  __syncthreads();
  const int d = t & 127, part = t >> 7;
  const int cbeg = part * 64;
  float mx = -INFINITY;
  for (int c = cbeg; c < cbeg + 64; ++c) mx = fmaxf(mx, klds[c][d]);
  red[part][d] = mx;
  __syncthreads();
  const float m = fmaxf(red[0][d], red[1][d]);
  __syncthreads();
  float sum = 0.f;
  for (int c = cbeg; c < cbeg + 64; ++c) {
    const float e = __expf(klds[c][d] - m);
    sum += e;
    *swz(eT, d, c) = f2bf(e);
  }
  red[part][d] = sum;
  __syncthreads();
  const float Av = red[0][d] + red[1][d];
  if (part == 0) {
    mloc[(size_t)bid * HD + d] = m;
    aloc[(size_t)bid * HD + d] = Av;
  }
  // B[d][e] = sum_c eT[d][c] * vT[e][c]
  const int lane = t & 63, w = t >> 6, wm = w >> 1, wn = w & 1;
  const int l15 = lane & 15, l4 = lane >> 4;
  f32x4 acc[4][4] = {};
#pragma unroll
  for (int kk2 = 0; kk2 < 4; ++kk2) {
    bf16x8 af[4], bfr[4];
#pragma unroll
    for (int mm = 0; mm < 4; ++mm)
      af[mm] = *(const bf16x8*)swz(eT, wm * 64 + mm * 16 + l15, kk2 * 32 + l4 * 8);
#pragma unroll
    for (int nn = 0; nn < 4; ++nn)
      bfr[nn] = *(const bf16x8*)swz(vT, wn * 64 + nn * 16 + l15, kk2 * 32 + l4 * 8);
#pragma unroll
    for (int mm = 0; mm < 4; ++mm)
#pragma unroll
      for (int nn = 0; nn < 4; ++nn)
        acc[mm][nn] = mfma16(af[mm], bfr[nn], acc[mm][nn]);
  }
  float* bout = bloc + (size_t)bid * HD * HD;
#pragma unroll
  for (int mm = 0; mm < 4; ++mm) {
    const int r0 = wm * 64 + mm * 16 + l4 * 4;
#pragma unroll
    for (int nn = 0; nn < 4; ++nn) {
      const int cc = wn * 64 + nn * 16 + l15;
#pragma unroll
      for (int i = 0; i < 4; ++i)
        bout[(size_t)(r0 + i) * HD + cc] = acc[mm][nn][i];
    }
  }
}

// ------- online scan over 32 chunks: kv[nc][bk][d][e] = B_run/A_run --------
__global__ __launch_bounds__(256) void k_scan_kv(
    const float* __restrict__ mloc, const float* __restrict__ aloc,
    const float* __restrict__ bloc, u16* __restrict__ kv) {
  const int gw = blockIdx.x * 4 + (threadIdx.x >> 6);  // (bk)*128 + d
  const int lane = threadIdx.x & 63;
  const int d = gw & 127, bk = gw >> 7;
  float m = -INFINITY, A = 0.f, B0 = 0.f, B1 = 0.f;
  for (int nc = 0; nc < NCH; ++nc) {
    const size_t sb = ((size_t)bk * NCH + nc) * HD + d;
    const float ml = mloc[sb], Alc = aloc[sb];
    const float2 Bl = *(const float2*)(bloc + sb * HD + lane * 2);
    const float mn = fmaxf(m, ml);
    const float so = __expf(m - mn), sn = __expf(ml - mn);
    A = A * so + Alc * sn;
    B0 = B0 * so + Bl.x * sn;
    B1 = B1 * so + Bl.y * sn;
    m = mn;
    const float inv = 1.0f / A;
    u16x2 o = { f2bf(B0 * inv), f2bf(B1 * inv) };
    *(u16x2*)(kv + (((size_t)nc * 16 + bk) * HD + d) * HD + lane * 2) = o;
  }
}

// ------- per-(b,h,chunk): attn[c][e] = q_sm[c][:] @ kv[:][e] (MFMA) --------
__global__ __launch_bounds__(256) void k_attn_out(
    const u16* __restrict__ qsm, const u16* __restrict__ kv,
    u16* __restrict__ attn) {
  const int bid = blockIdx.x;                    // (b*NH+h)*NCH + nc
  const int nc = bid & 31, h = (bid >> 5) & 31, b = bid >> 10;
  const int bk = b * 8 + (h >> 2);
  __shared__ __align__(16) u16 ql[CH * HD];      // [c][d] swizzled
  __shared__ __align__(16) u16 kvT[HD * HD];     // [e][d] swizzled
  const int t = threadIdx.x;
  const u16* qbase = qsm + ((size_t)(b * NH + h) * SEQL + nc * CH) * HD;
#pragma unroll
  for (int i = 0; i < 8; ++i) {
    const int idx = i * 256 + t;
    const int c = idx >> 4, col = (idx & 15) * 8;
    *(u16x8*)swz(ql, c, col) = *(const u16x8*)(qbase + (size_t)c * HD + col);
  }
  const u16* kvbase = kv + ((size_t)nc * 16 + bk) * HD * HD;
  for (int i = 0; i < 32; ++i) {
    const int idx = i * 256 + t;
    const int dd = idx >> 6, e0 = (idx & 63) * 2;
    const u16x2 p = *(const u16x2*)(kvbase + (size_t)dd * HD + e0);
    *swz(kvT, e0, dd) = p[0];
    *swz(kvT, e0 + 1, dd) = p[1];
  }
  __syncthreads();
  const int lane = t & 63, w = t >> 6, wm = w >> 1, wn = w & 1;
  const int l15 = lane & 15, l4 = lane >> 4;
  f32x4 acc[4][4] = {};
#pragma unroll
  for (int kk2 = 0; kk2 < 4; ++kk2) {
    bf16x8 af[4], bfr[4];
#pragma unroll
    for (int mm = 0; mm < 4; ++mm)
      af[mm] = *(const bf16x8*)swz(ql, wm * 64 + mm * 16 + l15, kk2 * 32 + l4 * 8);
#pragma unroll
    for (int nn = 0; nn < 4; ++nn)
      bfr[nn] = *(const bf16x8*)swz(kvT, wn * 64 + nn * 16 + l15, kk2 * 32 + l4 * 8);
#pragma unroll
    for (int mm = 0; mm < 4; ++mm)
#pragma unroll
      for (int nn = 0; nn < 4; ++nn)
        acc[mm][nn] = mfma16(af[mm], bfr[nn], acc[mm][nn]);
  }
  u16* obase = attn + ((size_t)(b * SEQL + nc * CH)) * DIMM + h * HD;
#pragma unroll
  for (int mm = 0; mm < 4; ++mm) {
    const int r0 = wm * 64 + mm * 16 + l4 * 4;
#pragma unroll
    for (int nn = 0; nn < 4; ++nn) {
      const int cc = wn * 64 + nn * 16 + l15;
#pragma unroll
      for (int i = 0; i < 4; ++i)
        obase[(size_t)(r0 + i) * DIMM + cc] = f2bf(acc[mm][nn][i]);
    }
  }
}

extern "C" void kernel_launch(void* const* d_in, const int* in_sizes, int n_in,
                              void* d_out, int out_size, void* d_ws, size_t ws_size,
                              hipStream_t stream) {
  const float* x  = (const float*)d_in[0];
  const float* fc = (const float*)d_in[1];
  const float* wq = (const float*)d_in[2];
  const float* wk = (const float*)d_in[3];
  const float* wv = (const float*)d_in[4];
  const float* wo = (const float*)d_in[5];
  float* out = (float*)d_out;
  char* ws = (char*)d_ws;
  size_t off = 0;
  auto take = [&](size_t bytes) {
    char* p = ws + off;
    off += (bytes + 255) & ~(size_t)255;
    return p;
  };
  u16* xb   = (u16*)take((size_t)8192 * 4096 * 2);   //  64 MiB
  u16* wqb  = (u16*)take((size_t)4096 * 4096 * 2);   //  32 MiB
  u16* wkb  = (u16*)take((size_t)1024 * 4096 * 2);   //   8 MiB
  u16* wvb  = (u16*)take((size_t)1024 * 4096 * 2);   //   8 MiB
  u16* wob  = (u16*)take((size_t)4096 * 4096 * 2);   //  32 MiB
  float* xk = (float*)take((size_t)8192 * 1024 * 4); //  32 MiB
  float* xv = (float*)take((size_t)8192 * 1024 * 4); //  32 MiB
  u16* qsm  = (u16*)take((size_t)8192 * 4096 * 2);   //  64 MiB
  float* mloc = (float*)take((size_t)512 * 128 * 4);
  float* aloc = (float*)take((size_t)512 * 128 * 4);
  u16* kvb  = (u16*)take((size_t)512 * 128 * 128 * 2); // 16 MiB
  float* bloc = (float*)take((size_t)512 * 128 * 128 * 4); // 32 MiB
  // attn (bf16, 64 MiB) aliases xk+xv (both consumed before attn is written)
  u16* attn = (u16*)xk;

  k_cvt<<<8388608 / 256, 256, 0, stream>>>(x,  xb,  8388608);
  k_cvt<<<4194304 / 256, 256, 0, stream>>>(wq, wqb, 4194304);
  k_cvt<<<1048576 / 256, 256, 0, stream>>>(wk, wkb, 1048576);
  k_cvt<<<1048576 / 256, 256, 0, stream>>>(wv, wvb, 1048576);
  k_cvt<<<4194304 / 256, 256, 0, stream>>>(wo, wob, 4194304);

  // xq GEMM with fused RoPE+softmax -> qsm (bf16, [b][h][s][d])
  k_gemm<1><<<dim3(32, 64), 256, 0, stream>>>(xb, wqb, qsm, fc, 8192, 4096, 4096);
  k_gemm<0><<<dim3(8, 64),  256, 0, stream>>>(xb, wkb, xk, nullptr, 8192, 1024, 4096);
  k_gemm<0><<<dim3(8, 64),  256, 0, stream>>>(xb, wvb, xv, nullptr, 8192, 1024, 4096);

  k_chunk_stats<<<512, 256, 0, stream>>>(xk, xv, fc, mloc, aloc, bloc);
  k_scan_kv<<<512, 256, 0, stream>>>(mloc, aloc, bloc, kvb);
  k_attn_out<<<2048, 256, 0, stream>>>(qsm, kvb, attn);

  k_gemm<0><<<dim3(32, 64), 256, 0, stream>>>(attn, wob, out, nullptr, 8192, 4096, 4096);
}